// Round 10
// baseline (166.579 us; speedup 1.0000x reference)
//
#include <hip/hip_runtime.h>
#include <hip/hip_bf16.h>

#define FDIM 256
#define ZW   512
#define DNB  32
#define NMAX 100000

typedef __attribute__((ext_vector_type(8))) short bf16x8;
typedef __attribute__((ext_vector_type(4))) float f32x4;

// Fallback scratch in BSS (used only if ws_size is too small).
__device__ __align__(16) unsigned short g_Zb[(size_t)NMAX * ZW];   // 102.4 MB
__device__ float g_degb[NMAX];
// Small weight tables (L2-resident).
__device__ __align__(16) unsigned short g_Wz[ZW * FDIM];  // [c][k]: c<256 W2a, c>=256 C1
__device__ float g_c2[FDIM];
__device__ float g_c3[FDIM];

__device__ __forceinline__ unsigned short f2bf(float f) {
    __hip_bfloat16 h = __float2bfloat16(f);
    return *reinterpret_cast<unsigned short*>(&h);
}
__device__ __forceinline__ float bf2f(unsigned short u) {
    return __uint_as_float(((unsigned)u) << 16);
}

// ---------- 1) prep_w: g_Wz [512][256] bf16, c2, c3, degree table ----------
__global__ __launch_bounds__(256) void prep_w(const float* __restrict__ W1,
                                              const float* __restrict__ W2,
                                              const float* __restrict__ b1,
                                              const float* __restrict__ b2,
                                              const float* __restrict__ feats,
                                              float* deg_p,
                                              float Dmul, int N) {
    float* deg = deg_p ? deg_p : g_degb;
    __shared__ float w2s[FDIM];
    __shared__ float rv[4], ru[4];
    int o = blockIdx.x, tid = threadIdx.x;

    // degree table: 65536 threads grid-stride over N
    for (size_t n = (size_t)o * 256 + tid; n < (size_t)N; n += 65536)
        deg[n] = feats[n * FDIM];

    w2s[tid] = W2[(size_t)o * ZW + FDIM + tid];
    __syncthreads();

    const float* w1a = W1 + tid;           // column k0 = tid       -> C1[o][tid]
    const float* w1b = W1 + FDIM + tid;    // column k1 = 256+tid   -> c2 sum
    float acc0 = 0.f, acc1 = 0.f;
    for (int j = 0; j < FDIM; j += 8) {
        float r0[8], r1[8];
        #pragma unroll
        for (int u = 0; u < 8; ++u) {
            r0[u] = w1a[(size_t)(j + u) * ZW];
            r1[u] = w1b[(size_t)(j + u) * ZW];
        }
        #pragma unroll
        for (int u = 0; u < 8; ++u) {
            acc0 = fmaf(w2s[j + u], r0[u], acc0);
            acc1 = fmaf(w2s[j + u], r1[u], acc1);
        }
    }
    g_Wz[(size_t)(FDIM + o) * FDIM + tid] = f2bf(acc0);              // C1 row o
    g_Wz[(size_t)o * FDIM + tid] = f2bf(W2[(size_t)o * ZW + tid]);   // W2a row o

    float v = acc1;
    float u = b1[tid] * w2s[tid];
    #pragma unroll
    for (int s = 32; s; s >>= 1) { v += __shfl_down(v, s); u += __shfl_down(u, s); }
    if ((tid & 63) == 0) { rv[tid >> 6] = v; ru[tid >> 6] = u; }
    __syncthreads();
    if (tid == 0) {
        g_c2[o] = rv[0] + rv[1] + rv[2] + rv[3];
        g_c3[o] = b2[o] + Dmul * (ru[0] + ru[1] + ru[2] + ru[3]);
    }
}

// ---------- 2) zgemm: Z[n][0:256]=FD[n]@W2a^T, Z[n][256:512]=FD[n]@C1^T ----------
// 32 rows/block. Stage fp32->bf16 LDS; MFMA with SWAPPED operands (A=weights)
// so D rows = out-cols -> lane holds 4 consecutive cols -> 8B packed stores.
__global__ __launch_bounds__(256) void zgemm(const float* __restrict__ fd,
                                             unsigned short* Z_p, int N) {
    unsigned short* Z = Z_p ? Z_p : g_Zb;
    __shared__ __align__(16) char lds[32 * 1024];  // in-stage 16KB; out-stage 32KB (reused)

    int tid = threadIdx.x, wave = tid >> 6, lane = tid & 63;
    int l15 = lane & 15, lg = lane >> 4;
    int base = blockIdx.x * 32;
    const float4* fd4 = (const float4*)fd;

    // ---- stage-in: wave w -> rows w*8..+7; lane: 16B fp32 -> 8B bf16, swizzled
    #pragma unroll
    for (int i = 0; i < 8; ++i) {
        int row = wave * 8 + i;
        int n = base + row;
        float4 v = make_float4(0.f, 0.f, 0.f, 0.f);
        if (n < N) v = fd4[(size_t)n * 64 + lane];
        ushort4 h = make_ushort4(f2bf(v.x), f2bf(v.y), f2bf(v.z), f2bf(v.w));
        *(ushort4*)(lds + row * 512 + ((lane * 8) ^ ((row & 7) << 4))) = h;
    }
    __syncthreads();

    // ---- MFMA: wave w -> out-cols w*128 (8 tiles); node rows 0..31 (2 tiles)
    int swzB = (l15 & 7) << 4;
    f32x4 acc[2][8];
    #pragma unroll
    for (int mt = 0; mt < 2; ++mt)
        #pragma unroll
        for (int nt = 0; nt < 8; ++nt) acc[mt][nt] = (f32x4){0.f, 0.f, 0.f, 0.f};

    const char* pB0 = lds + (size_t)l15 * 512;
    const char* pB1 = lds + (size_t)(16 + l15) * 512;
    const unsigned short* wA = g_Wz + (size_t)(wave * 128 + l15) * FDIM + lg * 8;

    #pragma unroll 2
    for (int kk = 0; kk < FDIM; kk += 32) {
        int kb = kk * 2 + lg * 16;
        bf16x8 b0 = *(const bf16x8*)(pB0 + (kb ^ swzB));
        bf16x8 b1 = *(const bf16x8*)(pB1 + (kb ^ swzB));
        #pragma unroll
        for (int nt = 0; nt < 8; ++nt) {
            bf16x8 a = *(const bf16x8*)(wA + (size_t)nt * 16 * FDIM + kk);
            // D[col=l15 -> node row][row=reg -> out-col]
            acc[0][nt] = __builtin_amdgcn_mfma_f32_16x16x32_bf16(a, b0, acc[0][nt], 0, 0, 0);
            acc[1][nt] = __builtin_amdgcn_mfma_f32_16x16x32_bf16(a, b1, acc[1][nt], 0, 0, 0);
        }
    }
    __syncthreads();   // all LDS reads done -> safe to overwrite with out-stage

    // ---- out-stage: value (noderow = mt*16+l15, outcol0 = wave*128+nt*16+lg*4)
    #pragma unroll
    for (int mt = 0; mt < 2; ++mt)
        #pragma unroll
        for (int nt = 0; nt < 8; ++nt) {
            int nrow = mt * 16 + l15;
            int oc0 = wave * 128 + nt * 16 + lg * 4;
            ushort4 h = make_ushort4(f2bf(acc[mt][nt][0]), f2bf(acc[mt][nt][1]),
                                     f2bf(acc[mt][nt][2]), f2bf(acc[mt][nt][3]));
            *(ushort4*)(lds + nrow * 1024 + ((oc0 * 2) ^ ((nrow & 7) << 4))) = h;
        }
    __syncthreads();

    // ---- store: wave w rows w*8..+7, 16B/lane coalesced (1KB per row)
    #pragma unroll
    for (int i = 0; i < 8; ++i) {
        int row = wave * 8 + i;
        int n = base + row;
        if (n >= N) break;   // wave-uniform
        uint4 v = *(uint4*)(lds + row * 1024 + ((lane * 16) ^ ((row & 7) << 4)));
        *(uint4*)(Z + (size_t)n * ZW + lane * 8) = v;
    }
}

// ---------- 3) gather_norm: out[t] = L2norm(Z1[node] + sum Z2[nb] + Sdeg*c2 + c3)
__global__ __launch_bounds__(256, 6) void gather_norm(
    const unsigned short* Z_p, const float* deg_p,
    const int* __restrict__ adj,
    const int* __restrict__ in1, int B1,
    const int* __restrict__ in2, int B2,
    const int* __restrict__ neg, int total,
    float* __restrict__ out)
{
    const unsigned short* Z = Z_p ? Z_p : g_Zb;
    const float* deg = deg_p ? deg_p : g_degb;

    int wave = threadIdx.x >> 6, lane = threadIdx.x & 63;
    int t = blockIdx.x * 4 + wave;
    if (t >= total) return;
    int node = (t < B1) ? in1[t] : ((t < B1 + B2) ? in2[t - B1] : neg[t - B1 - B2]);

    int idx = 0; float dg = 0.f;
    if (lane < DNB) {
        idx = adj[(size_t)node * DNB + lane];
        dg = deg[idx];
    }
    #pragma unroll
    for (int s = 16; s; s >>= 1) dg += __shfl_down(dg, s);
    float sd = __shfl(dg, 0);

    // Z1 row of the node (cols 0..255): 8B/lane = 512B per wave-load
    ushort4 z1 = *(const ushort4*)(Z + (size_t)node * ZW + lane * 4);
    float a0 = bf2f(z1.x), a1 = bf2f(z1.y), a2 = bf2f(z1.z), a3 = bf2f(z1.w);

    // neighbor Z2 rows (cols 256..511), 8 rows in flight
    #pragma unroll
    for (int d = 0; d < DNB; d += 8) {
        ushort4 v[8];
        #pragma unroll
        for (int u = 0; u < 8; ++u) {
            int nb = __shfl(idx, d + u);
            v[u] = *(const ushort4*)(Z + (size_t)nb * ZW + FDIM + lane * 4);
        }
        #pragma unroll
        for (int u = 0; u < 8; ++u) {
            a0 += bf2f(v[u].x);
            a1 += bf2f(v[u].y);
            a2 += bf2f(v[u].z);
            a3 += bf2f(v[u].w);
        }
    }

    float4 c2v = *(const float4*)(g_c2 + lane * 4);
    float4 c3v = *(const float4*)(g_c3 + lane * 4);
    float v0 = a0 + sd * c2v.x + c3v.x;
    float v1 = a1 + sd * c2v.y + c3v.y;
    float v2 = a2 + sd * c2v.z + c3v.z;
    float v3 = a3 + sd * c2v.w + c3v.w;

    float ss = v0 * v0 + v1 * v1 + v2 * v2 + v3 * v3;
    #pragma unroll
    for (int s = 32; s; s >>= 1) ss += __shfl_xor(ss, s);
    float inv = 1.0f / fmaxf(sqrtf(ss), 1e-12f);
    float4 o = make_float4(v0 * inv, v1 * inv, v2 * inv, v3 * inv);
    *(float4*)(out + (size_t)t * FDIM + lane * 4) = o;
}

extern "C" void kernel_launch(void* const* d_in, const int* in_sizes, int n_in,
                              void* d_out, int out_size, void* d_ws, size_t ws_size,
                              hipStream_t stream) {
    const float* feat_data = (const float*)d_in[0];
    const float* feats     = (const float*)d_in[1];
    const float* W1        = (const float*)d_in[2];
    const float* b1        = (const float*)d_in[3];
    const float* W2        = (const float*)d_in[4];
    const float* b2        = (const float*)d_in[5];
    const int*   adj       = (const int*)d_in[6];
    const int*   in1       = (const int*)d_in[7];
    const int*   in2       = (const int*)d_in[8];
    const int*   neg       = (const int*)d_in[9];

    int B1 = in_sizes[7];
    int B2 = in_sizes[8];
    int Bn = in_sizes[9];
    int N  = in_sizes[0] / FDIM;
    int D  = in_sizes[6] / N;   // == 32

    float* out = (float*)d_out;
    int total = B1 + B2 + Bn;

    // ws layout: [Z bf16 N*512][deg f32 N]
    size_t z_bytes = (size_t)N * ZW * 2;
    size_t need = z_bytes + ((size_t)N * 4 + 255);
    bool usews = (ws_size >= need);
    unsigned short* Zp = usews ? (unsigned short*)d_ws : nullptr;
    float* degp = usews ? (float*)((char*)d_ws + ((z_bytes + 255) & ~(size_t)255)) : nullptr;

    prep_w<<<FDIM, 256, 0, stream>>>(W1, W2, b1, b2, feats, degp, (float)D, N);
    zgemm<<<(N + 31) / 32, 256, 0, stream>>>(feat_data, Zp, N);
    gather_norm<<<(total + 3) / 4, 256, 0, stream>>>(Zp, degp, adj, in1, B1,
                                                     in2, B2, neg, total, out);
}

// Round 12
// 117.260 us; speedup vs baseline: 1.4206x; 1.4206x over previous
//
#include <hip/hip_runtime.h>
#include <hip/hip_bf16.h>

#define FDIM 256
#define K2   512
#define DNB  32
#define NMAX 100000
#define CONVB 2048

typedef __attribute__((ext_vector_type(8))) short bf16x8;
typedef __attribute__((ext_vector_type(4))) float f32x4;
typedef __attribute__((ext_vector_type(4))) unsigned int u32x4;

// Fallback scratch in BSS (used only if ws_size is too small).
__device__ __align__(16) unsigned short g_FDb[(size_t)NMAX * FDIM];
__device__ float g_degb[NMAX];
// Small combined-weight arrays (L2-resident, read-heavy).
__device__ __align__(16) unsigned short g_Wc[FDIM * K2];   // [o][k] bf16
__device__ float g_c2[FDIM];
__device__ float g_c3[FDIM];

__device__ __forceinline__ unsigned short f2bf(float f) {
    __hip_bfloat16 h = __float2bfloat16(f);
    return *reinterpret_cast<unsigned short*>(&h);
}
__device__ __forceinline__ float bf2f(unsigned short u) {
    return __uint_as_float(((unsigned)u) << 16);
}
__device__ __forceinline__ unsigned int pack2(float lo, float hi) {
    return (unsigned int)f2bf(lo) | ((unsigned int)f2bf(hi) << 16);
}

// ---------- 1) build_prep ----------
// blocks [0,256): weight combine + c2/c3 + degree table
// blocks [256,256+CONVB): fp32 -> bf16 table with NON-TEMPORAL load+store
__global__ __launch_bounds__(256) void build_prep(
    const float* __restrict__ fd,
    const float* __restrict__ feats,
    const float* __restrict__ W1,
    const float* __restrict__ W2,
    const float* __restrict__ b1,
    const float* __restrict__ b2,
    float Dmul, int N,
    unsigned short* tab_p, float* deg_p)
{
    unsigned short* tab = tab_p ? tab_p : g_FDb;
    float* deg = deg_p ? deg_p : g_degb;
    int bid = blockIdx.x;
    int tid = threadIdx.x;

    if (bid >= 256) {
        // ---- conversion: grid-stride, 4-deep, NT loads + NT stores
        size_t tidg = (size_t)(bid - 256) * 256 + tid;
        size_t nthr = (size_t)CONVB * 256;
        size_t total8 = (size_t)N * (FDIM / 8);   // # 16B output groups
        const f32x4* in4 = (const f32x4*)fd;
        u32x4* out8 = (u32x4*)tab;

        size_t i = tidg;
        for (; i + 3 * nthr < total8; i += 4 * nthr) {
            f32x4 a[4], b[4];
            #pragma unroll
            for (int j = 0; j < 4; ++j) {
                size_t g = i + (size_t)j * nthr;
                a[j] = __builtin_nontemporal_load(in4 + 2 * g);
                b[j] = __builtin_nontemporal_load(in4 + 2 * g + 1);
            }
            #pragma unroll
            for (int j = 0; j < 4; ++j) {
                size_t g = i + (size_t)j * nthr;
                u32x4 o;
                o.x = pack2(a[j].x, a[j].y);
                o.y = pack2(a[j].z, a[j].w);
                o.z = pack2(b[j].x, b[j].y);
                o.w = pack2(b[j].z, b[j].w);
                __builtin_nontemporal_store(o, out8 + g);
            }
        }
        for (; i < total8; i += nthr) {
            f32x4 a = __builtin_nontemporal_load(in4 + 2 * i);
            f32x4 b = __builtin_nontemporal_load(in4 + 2 * i + 1);
            u32x4 o;
            o.x = pack2(a.x, a.y);
            o.y = pack2(a.z, a.w);
            o.z = pack2(b.x, b.y);
            o.w = pack2(b.z, b.w);
            __builtin_nontemporal_store(o, out8 + i);
        }
        return;
    }

    // ---- weight combine (R8-validated): o = bid
    __shared__ float w2s[FDIM];
    __shared__ float rv[4], ru[4];
    int o = bid;

    // degree table: 65536 threads grid-stride over N
    for (size_t n = (size_t)o * 256 + tid; n < (size_t)N; n += 65536)
        deg[n] = feats[n * FDIM];

    w2s[tid] = W2[(size_t)o * K2 + FDIM + tid];
    __syncthreads();

    const float* w1a = W1 + tid;           // column k0 = tid       -> C1
    const float* w1b = W1 + FDIM + tid;    // column k1 = 256+tid   -> c2 sum
    float acc0 = 0.f, acc1 = 0.f;
    for (int j = 0; j < FDIM; j += 8) {
        float r0[8], r1[8];
        #pragma unroll
        for (int u = 0; u < 8; ++u) {
            r0[u] = w1a[(size_t)(j + u) * K2];
            r1[u] = w1b[(size_t)(j + u) * K2];
        }
        #pragma unroll
        for (int u = 0; u < 8; ++u) {
            acc0 = fmaf(w2s[j + u], r0[u], acc0);
            acc1 = fmaf(w2s[j + u], r1[u], acc1);
        }
    }
    g_Wc[(size_t)o * K2 + FDIM + tid] = f2bf(acc0);
    g_Wc[(size_t)o * K2 + tid]        = f2bf(W2[(size_t)o * K2 + tid]);

    float v = acc1;
    float u = b1[tid] * w2s[tid];
    #pragma unroll
    for (int s = 32; s; s >>= 1) { v += __shfl_down(v, s); u += __shfl_down(u, s); }
    if ((tid & 63) == 0) { rv[tid >> 6] = v; ru[tid >> 6] = u; }
    __syncthreads();
    if (tid == 0) {
        g_c2[o] = rv[0] + rv[1] + rv[2] + rv[3];
        g_c3[o] = b2[o] + Dmul * (ru[0] + ru[1] + ru[2] + ru[3]);
    }
}

// ---------- 2) gg_norm: gather -> LDS -> MFMA -> degree term -> L2 norm ----------
// 16 rows/block, 4 waves. Gather writes MFMA-swizzled LDS directly (no X array).
__global__ __launch_bounds__(256, 6) void gg_norm(
    const unsigned short* tab_p, const float* deg_p,
    const int* __restrict__ adj,
    const int* __restrict__ in1, int B1,
    const int* __restrict__ in2, int B2,
    const int* __restrict__ neg, int total,
    float* __restrict__ out)
{
    const unsigned short* tab = tab_p ? tab_p : g_FDb;
    const float* deg = deg_p ? deg_p : g_degb;

    __shared__ __align__(16) char lds[16 * 1024];   // bf16 [16][512]; reused f32 [16][256]
    __shared__ float Sdeg[16];

    int tid = threadIdx.x, wave = tid >> 6, lane = tid & 63;
    int base = blockIdx.x * 16;

    // ---- gather phase: wave handles rows wave*4 .. +3
    #pragma unroll
    for (int i = 0; i < 4; ++i) {
        int row = wave * 4 + i;
        int t = base + row;
        char* rowp = lds + row * 1024;
        int swz = (row & 7) << 4;
        int boff = (lane * 8) ^ swz;
        if (t >= total) {
            ushort4 z = make_ushort4(0, 0, 0, 0);
            *(ushort4*)(rowp + boff) = z;
            *(ushort4*)(rowp + 512 + boff) = z;
            if (lane == 0) Sdeg[row] = 0.f;
            continue;   // wave-uniform
        }
        int node = (t < B1) ? in1[t] : ((t < B1 + B2) ? in2[t - B1] : neg[t - B1 - B2]);

        int idx = 0; float dg = 0.f;
        if (lane < DNB) {
            idx = adj[(size_t)node * DNB + lane];
            dg = deg[idx];
        }
        #pragma unroll
        for (int s = 16; s; s >>= 1) dg += __shfl_down(dg, s);
        if (lane == 0) Sdeg[row] = dg;

        // node row passthrough (bf16): 8B/lane = full 512B row per wave-load
        ushort4 nf = *(const ushort4*)(tab + (size_t)node * FDIM + lane * 4);
        *(ushort4*)(rowp + boff) = nf;

        float a0 = 0.f, a1 = 0.f, a2 = 0.f, a3 = 0.f;
        #pragma unroll
        for (int d = 0; d < DNB; d += 8) {
            ushort4 v[8];
            #pragma unroll
            for (int u = 0; u < 8; ++u) {
                int nb = __shfl(idx, d + u);
                v[u] = *(const ushort4*)(tab + (size_t)nb * FDIM + lane * 4);
            }
            #pragma unroll
            for (int u = 0; u < 8; ++u) {
                a0 += bf2f(v[u].x);
                a1 += bf2f(v[u].y);
                a2 += bf2f(v[u].z);
                a3 += bf2f(v[u].w);
            }
        }
        *(ushort4*)(rowp + 512 + boff) =
            make_ushort4(f2bf(a0), f2bf(a1), f2bf(a2), f2bf(a3));
    }
    __syncthreads();

    // ---- MFMA: wave w -> cols w*64 (4 tiles of 16); 16 rows (1 tile)
    int l15 = lane & 15, lg = lane >> 4;
    int swzA = (l15 & 7) << 4;
    f32x4 acc[4];
    #pragma unroll
    for (int nt = 0; nt < 4; ++nt) acc[nt] = (f32x4){0.f, 0.f, 0.f, 0.f};

    const char* pA = lds + (size_t)l15 * 1024;
    const unsigned short* wcB = g_Wc + (size_t)(wave * 64 + l15) * K2 + lg * 8;

    #pragma unroll 4
    for (int kk = 0; kk < K2; kk += 32) {
        int kb = kk * 2 + lg * 16;
        bf16x8 a0 = *(const bf16x8*)(pA + (kb ^ swzA));
        #pragma unroll
        for (int nt = 0; nt < 4; ++nt) {
            bf16x8 b = *(const bf16x8*)(wcB + (size_t)nt * 16 * K2 + kk);
            acc[nt] = __builtin_amdgcn_mfma_f32_16x16x32_bf16(a0, b, acc[nt], 0, 0, 0);
        }
    }
    __syncthreads();   // LDS reads done -> safe to overwrite with f32 stage

    // ---- stage raw acc to LDS as f32 [16][256] (HW-verified D layout)
    float* outf = (float*)lds;
    #pragma unroll
    for (int nt = 0; nt < 4; ++nt)
        #pragma unroll
        for (int r = 0; r < 4; ++r) {
            int row = lg * 4 + r;
            int col = wave * 64 + nt * 16 + l15;
            outf[row * 256 + col] = acc[nt][r];
        }
    __syncthreads();

    // ---- epilogue: wave handles rows wave*4 .. +3
    float4 c2v = *(const float4*)(g_c2 + lane * 4);
    float4 c3v = *(const float4*)(g_c3 + lane * 4);
    #pragma unroll
    for (int r = 0; r < 4; ++r) {
        int row = wave * 4 + r;
        int t = base + row;
        if (t >= total) break;                   // wave-uniform
        float sd = Sdeg[row];
        float4 v = *(float4*)(outf + row * 256 + lane * 4);
        v.x += sd * c2v.x + c3v.x;
        v.y += sd * c2v.y + c3v.y;
        v.z += sd * c2v.z + c3v.z;
        v.w += sd * c2v.w + c3v.w;
        float ss = v.x * v.x + v.y * v.y + v.z * v.z + v.w * v.w;
        #pragma unroll
        for (int s = 32; s; s >>= 1) ss += __shfl_xor(ss, s);
        float inv = 1.0f / fmaxf(sqrtf(ss), 1e-12f);
        v.x *= inv; v.y *= inv; v.z *= inv; v.w *= inv;
        *(float4*)(out + (size_t)t * FDIM + lane * 4) = v;
    }
}

extern "C" void kernel_launch(void* const* d_in, const int* in_sizes, int n_in,
                              void* d_out, int out_size, void* d_ws, size_t ws_size,
                              hipStream_t stream) {
    const float* feat_data = (const float*)d_in[0];
    const float* feats     = (const float*)d_in[1];
    const float* W1        = (const float*)d_in[2];
    const float* b1        = (const float*)d_in[3];
    const float* W2        = (const float*)d_in[4];
    const float* b2        = (const float*)d_in[5];
    const int*   adj       = (const int*)d_in[6];
    const int*   in1       = (const int*)d_in[7];
    const int*   in2       = (const int*)d_in[8];
    const int*   neg       = (const int*)d_in[9];

    int B1 = in_sizes[7];
    int B2 = in_sizes[8];
    int Bn = in_sizes[9];
    int N  = in_sizes[0] / FDIM;
    int D  = in_sizes[6] / N;   // == 32

    float* out = (float*)d_out;
    int total = B1 + B2 + Bn;

    // ws layout: [tab bf16 N*256][deg f32 N]
    size_t tab_bytes = (size_t)N * FDIM * 2;
    size_t need = ((tab_bytes + 255) & ~(size_t)255) + (size_t)N * 4;
    bool usews = (ws_size >= need);
    unsigned short* tab = usews ? (unsigned short*)d_ws : nullptr;
    float* deg = usews ? (float*)((char*)d_ws + ((tab_bytes + 255) & ~(size_t)255)) : nullptr;

    build_prep<<<256 + CONVB, 256, 0, stream>>>(feat_data, feats, W1, W2, b1, b2,
                                                (float)D, N, tab, deg);
    gg_norm<<<(total + 15) / 16, 256, 0, stream>>>(tab, deg, adj, in1, B1,
                                                   in2, B2, neg, total, out);
}

// Round 13
// 116.130 us; speedup vs baseline: 1.4344x; 1.0097x over previous
//
#include <hip/hip_runtime.h>
#include <hip/hip_bf16.h>

#define FDIM 256
#define K2   512
#define DNB  32
#define NMAX 100000
#define CONVB 2048

typedef __attribute__((ext_vector_type(8))) short bf16x8;
typedef __attribute__((ext_vector_type(4))) float f32x4;
typedef __attribute__((ext_vector_type(4))) unsigned int u32x4;

// Fallback scratch in BSS (used only if ws_size is too small).
__device__ __align__(16) unsigned short g_FDb[(size_t)NMAX * FDIM];
__device__ float g_degb[NMAX];
// Small combined-weight arrays (L2-resident, read-heavy).
__device__ __align__(16) unsigned short g_Wc[FDIM * K2];   // [o][k] bf16
__device__ float g_c2[FDIM];
__device__ float g_c3[FDIM];

__device__ __forceinline__ unsigned short f2bf(float f) {
    __hip_bfloat16 h = __float2bfloat16(f);
    return *reinterpret_cast<unsigned short*>(&h);
}
__device__ __forceinline__ float bf2f(unsigned short u) {
    return __uint_as_float(((unsigned)u) << 16);
}
__device__ __forceinline__ unsigned int pack2(float lo, float hi) {
    return (unsigned int)f2bf(lo) | ((unsigned int)f2bf(hi) << 16);
}

// ---------- 1) build_prep (R12-validated, NT conversion ~30us) ----------
__global__ __launch_bounds__(256) void build_prep(
    const float* __restrict__ fd,
    const float* __restrict__ feats,
    const float* __restrict__ W1,
    const float* __restrict__ W2,
    const float* __restrict__ b1,
    const float* __restrict__ b2,
    float Dmul, int N,
    unsigned short* tab_p, float* deg_p)
{
    unsigned short* tab = tab_p ? tab_p : g_FDb;
    float* deg = deg_p ? deg_p : g_degb;
    int bid = blockIdx.x;
    int tid = threadIdx.x;

    if (bid >= 256) {
        // ---- conversion: grid-stride, 4-deep, NT loads + NT stores
        size_t tidg = (size_t)(bid - 256) * 256 + tid;
        size_t nthr = (size_t)CONVB * 256;
        size_t total8 = (size_t)N * (FDIM / 8);   // # 16B output groups
        const f32x4* in4 = (const f32x4*)fd;
        u32x4* out8 = (u32x4*)tab;

        size_t i = tidg;
        for (; i + 3 * nthr < total8; i += 4 * nthr) {
            f32x4 a[4], b[4];
            #pragma unroll
            for (int j = 0; j < 4; ++j) {
                size_t g = i + (size_t)j * nthr;
                a[j] = __builtin_nontemporal_load(in4 + 2 * g);
                b[j] = __builtin_nontemporal_load(in4 + 2 * g + 1);
            }
            #pragma unroll
            for (int j = 0; j < 4; ++j) {
                size_t g = i + (size_t)j * nthr;
                u32x4 o;
                o.x = pack2(a[j].x, a[j].y);
                o.y = pack2(a[j].z, a[j].w);
                o.z = pack2(b[j].x, b[j].y);
                o.w = pack2(b[j].z, b[j].w);
                __builtin_nontemporal_store(o, out8 + g);
            }
        }
        for (; i < total8; i += nthr) {
            f32x4 a = __builtin_nontemporal_load(in4 + 2 * i);
            f32x4 b = __builtin_nontemporal_load(in4 + 2 * i + 1);
            u32x4 o;
            o.x = pack2(a.x, a.y);
            o.y = pack2(a.z, a.w);
            o.z = pack2(b.x, b.y);
            o.w = pack2(b.z, b.w);
            __builtin_nontemporal_store(o, out8 + i);
        }
        return;
    }

    // ---- weight combine: o = bid
    __shared__ float w2s[FDIM];
    __shared__ float rv[4], ru[4];
    int o = bid;

    for (size_t n = (size_t)o * 256 + tid; n < (size_t)N; n += 65536)
        deg[n] = feats[n * FDIM];

    w2s[tid] = W2[(size_t)o * K2 + FDIM + tid];
    __syncthreads();

    const float* w1a = W1 + tid;           // column k0 = tid       -> C1
    const float* w1b = W1 + FDIM + tid;    // column k1 = 256+tid   -> c2 sum
    float acc0 = 0.f, acc1 = 0.f;
    for (int j = 0; j < FDIM; j += 8) {
        float r0[8], r1[8];
        #pragma unroll
        for (int u = 0; u < 8; ++u) {
            r0[u] = w1a[(size_t)(j + u) * K2];
            r1[u] = w1b[(size_t)(j + u) * K2];
        }
        #pragma unroll
        for (int u = 0; u < 8; ++u) {
            acc0 = fmaf(w2s[j + u], r0[u], acc0);
            acc1 = fmaf(w2s[j + u], r1[u], acc1);
        }
    }
    g_Wc[(size_t)o * K2 + FDIM + tid] = f2bf(acc0);
    g_Wc[(size_t)o * K2 + tid]        = f2bf(W2[(size_t)o * K2 + tid]);

    float v = acc1;
    float u = b1[tid] * w2s[tid];
    #pragma unroll
    for (int s = 32; s; s >>= 1) { v += __shfl_down(v, s); u += __shfl_down(u, s); }
    if ((tid & 63) == 0) { rv[tid >> 6] = v; ru[tid >> 6] = u; }
    __syncthreads();
    if (tid == 0) {
        g_c2[o] = rv[0] + rv[1] + rv[2] + rv[3];
        g_c3[o] = b2[o] + Dmul * (ru[0] + ru[1] + ru[2] + ru[3]);
    }
}

// ---------- 2) gg_norm: 16 waves/block, ONE node per wave (R8 gather shape) ----------
__global__ __launch_bounds__(1024, 2) void gg_norm(
    const unsigned short* tab_p, const float* deg_p,
    const int* __restrict__ adj,
    const int* __restrict__ in1, int B1,
    const int* __restrict__ in2, int B2,
    const int* __restrict__ neg, int total,
    float* __restrict__ out)
{
    const unsigned short* tab = tab_p ? tab_p : g_FDb;
    const float* deg = deg_p ? deg_p : g_degb;

    __shared__ __align__(16) char lds[16 * 1024];   // bf16 [16][512]; reused f32 [16][256]
    __shared__ float Sdeg[16];

    int tid = threadIdx.x, wave = tid >> 6, lane = tid & 63;
    int base = blockIdx.x * 16;

    // ---- gather: wave handles row = wave (one node per wave)
    {
        int row = wave;
        int t = base + row;
        char* rowp = lds + row * 1024;
        int boff = (lane * 8) ^ ((row & 7) << 4);
        if (t >= total) {
            ushort4 z = make_ushort4(0, 0, 0, 0);
            *(ushort4*)(rowp + boff) = z;
            *(ushort4*)(rowp + 512 + boff) = z;
            if (lane == 0) Sdeg[row] = 0.f;
        } else {
            int node = (t < B1) ? in1[t] : ((t < B1 + B2) ? in2[t - B1] : neg[t - B1 - B2]);

            int idx = 0; float dg = 0.f;
            if (lane < DNB) {
                idx = adj[(size_t)node * DNB + lane];
                dg = deg[idx];
            }
            #pragma unroll
            for (int s = 16; s; s >>= 1) dg += __shfl_down(dg, s);
            if (lane == 0) Sdeg[row] = dg;

            // node row passthrough (bf16): 8B/lane = full 512B row per wave-load
            ushort4 nf = *(const ushort4*)(tab + (size_t)node * FDIM + lane * 4);
            *(ushort4*)(rowp + boff) = nf;

            float a0 = 0.f, a1 = 0.f, a2 = 0.f, a3 = 0.f;
            #pragma unroll
            for (int d = 0; d < DNB; d += 8) {
                ushort4 v[8];
                #pragma unroll
                for (int u = 0; u < 8; ++u) {
                    int nb = __shfl(idx, d + u);
                    v[u] = *(const ushort4*)(tab + (size_t)nb * FDIM + lane * 4);
                }
                #pragma unroll
                for (int u = 0; u < 8; ++u) {
                    a0 += bf2f(v[u].x);
                    a1 += bf2f(v[u].y);
                    a2 += bf2f(v[u].z);
                    a3 += bf2f(v[u].w);
                }
            }
            *(ushort4*)(rowp + 512 + boff) =
                make_ushort4(f2bf(a0), f2bf(a1), f2bf(a2), f2bf(a3));
        }
    }
    __syncthreads();

    // ---- MFMA: wave w -> col-tile w (cols w*16..+15); rows 0..15 (1 tile)
    int l15 = lane & 15, lg = lane >> 4;
    int swzA = (l15 & 7) << 4;
    f32x4 acc = (f32x4){0.f, 0.f, 0.f, 0.f};

    const char* pA = lds + (size_t)l15 * 1024;
    const unsigned short* wcB = g_Wc + (size_t)(wave * 16 + l15) * K2 + lg * 8;

    #pragma unroll 8
    for (int kk = 0; kk < K2; kk += 32) {
        int kb = kk * 2 + lg * 16;
        bf16x8 a0 = *(const bf16x8*)(pA + (kb ^ swzA));
        bf16x8 b = *(const bf16x8*)(wcB + kk);
        acc = __builtin_amdgcn_mfma_f32_16x16x32_bf16(a0, b, acc, 0, 0, 0);
    }
    __syncthreads();   // LDS reads done -> safe to overwrite with f32 stage

    // ---- stage raw acc to LDS as f32 [16][256] (HW-verified D layout)
    float* outf = (float*)lds;
    #pragma unroll
    for (int r = 0; r < 4; ++r) {
        int row = lg * 4 + r;
        int col = wave * 16 + l15;
        outf[row * 256 + col] = acc[r];
    }
    __syncthreads();

    // ---- epilogue: wave w handles row w
    {
        int row = wave;
        int t = base + row;
        if (t < total) {
            float4 c2v = *(const float4*)(g_c2 + lane * 4);
            float4 c3v = *(const float4*)(g_c3 + lane * 4);
            float sd = Sdeg[row];
            float4 v = *(float4*)(outf + row * 256 + lane * 4);
            v.x += sd * c2v.x + c3v.x;
            v.y += sd * c2v.y + c3v.y;
            v.z += sd * c2v.z + c3v.z;
            v.w += sd * c2v.w + c3v.w;
            float ss = v.x * v.x + v.y * v.y + v.z * v.z + v.w * v.w;
            #pragma unroll
            for (int s = 32; s; s >>= 1) ss += __shfl_xor(ss, s);
            float inv = 1.0f / fmaxf(sqrtf(ss), 1e-12f);
            v.x *= inv; v.y *= inv; v.z *= inv; v.w *= inv;
            *(float4*)(out + (size_t)t * FDIM + lane * 4) = v;
        }
    }
}

extern "C" void kernel_launch(void* const* d_in, const int* in_sizes, int n_in,
                              void* d_out, int out_size, void* d_ws, size_t ws_size,
                              hipStream_t stream) {
    const float* feat_data = (const float*)d_in[0];
    const float* feats     = (const float*)d_in[1];
    const float* W1        = (const float*)d_in[2];
    const float* b1        = (const float*)d_in[3];
    const float* W2        = (const float*)d_in[4];
    const float* b2        = (const float*)d_in[5];
    const int*   adj       = (const int*)d_in[6];
    const int*   in1       = (const int*)d_in[7];
    const int*   in2       = (const int*)d_in[8];
    const int*   neg       = (const int*)d_in[9];

    int B1 = in_sizes[7];
    int B2 = in_sizes[8];
    int Bn = in_sizes[9];
    int N  = in_sizes[0] / FDIM;
    int D  = in_sizes[6] / N;   // == 32

    float* out = (float*)d_out;
    int total = B1 + B2 + Bn;

    // ws layout: [tab bf16 N*256][deg f32 N]
    size_t tab_bytes = (size_t)N * FDIM * 2;
    size_t need = ((tab_bytes + 255) & ~(size_t)255) + (size_t)N * 4;
    bool usews = (ws_size >= need);
    unsigned short* tab = usews ? (unsigned short*)d_ws : nullptr;
    float* deg = usews ? (float*)((char*)d_ws + ((tab_bytes + 255) & ~(size_t)255)) : nullptr;

    build_prep<<<256 + CONVB, 256, 0, stream>>>(feat_data, feats, W1, W2, b1, b2,
                                                (float)D, N, tab, deg);
    gg_norm<<<(total + 15) / 16, 1024, 0, stream>>>(tab, deg, adj, in1, B1,
                                                    in2, B2, neg, total, out);
}

// Round 14
// 113.095 us; speedup vs baseline: 1.4729x; 1.0268x over previous
//
#include <hip/hip_runtime.h>
#include <hip/hip_bf16.h>

#define FDIM 256
#define K2   512
#define DNB  32
#define TM   32
#define NMAX 100000
#define TMAX 20480
#define CONVB 2048

typedef __attribute__((ext_vector_type(8))) short bf16x8;
typedef __attribute__((ext_vector_type(4))) float f32x4;
typedef __attribute__((ext_vector_type(4))) unsigned int u32x4;

// Fallback scratch in BSS (used only if ws_size is too small).
__device__ __align__(16) unsigned short g_FDb[(size_t)NMAX * FDIM];
__device__ __align__(16) unsigned short g_Xb[(size_t)TMAX * K2];
__device__ float g_degb[NMAX];
__device__ float g_Sdegb[TMAX];
// Small combined-weight arrays (L2-resident, read-heavy).
__device__ __align__(16) unsigned short g_Wc[FDIM * K2];   // [o][k] bf16
__device__ float g_c2[FDIM];
__device__ float g_c3[FDIM];

__device__ __forceinline__ unsigned short f2bf(float f) {
    __hip_bfloat16 h = __float2bfloat16(f);
    return *reinterpret_cast<unsigned short*>(&h);
}
__device__ __forceinline__ float bf2f(unsigned short u) {
    return __uint_as_float(((unsigned)u) << 16);
}
__device__ __forceinline__ unsigned int pack2(float lo, float hi) {
    return (unsigned int)f2bf(lo) | ((unsigned int)f2bf(hi) << 16);
}

// ---------- 1) build_prep (R12/R13-validated: NT conversion ~30us) ----------
__global__ __launch_bounds__(256) void build_prep(
    const float* __restrict__ fd,
    const float* __restrict__ feats,
    const float* __restrict__ W1,
    const float* __restrict__ W2,
    const float* __restrict__ b1,
    const float* __restrict__ b2,
    float Dmul, int N,
    unsigned short* tab_p, float* deg_p)
{
    unsigned short* tab = tab_p ? tab_p : g_FDb;
    float* deg = deg_p ? deg_p : g_degb;
    int bid = blockIdx.x;
    int tid = threadIdx.x;

    if (bid >= 256) {
        // ---- conversion: grid-stride, 4-deep, NT loads + NT stores
        size_t tidg = (size_t)(bid - 256) * 256 + tid;
        size_t nthr = (size_t)CONVB * 256;
        size_t total8 = (size_t)N * (FDIM / 8);   // # 16B output groups
        const f32x4* in4 = (const f32x4*)fd;
        u32x4* out8 = (u32x4*)tab;

        size_t i = tidg;
        for (; i + 3 * nthr < total8; i += 4 * nthr) {
            f32x4 a[4], b[4];
            #pragma unroll
            for (int j = 0; j < 4; ++j) {
                size_t g = i + (size_t)j * nthr;
                a[j] = __builtin_nontemporal_load(in4 + 2 * g);
                b[j] = __builtin_nontemporal_load(in4 + 2 * g + 1);
            }
            #pragma unroll
            for (int j = 0; j < 4; ++j) {
                size_t g = i + (size_t)j * nthr;
                u32x4 o;
                o.x = pack2(a[j].x, a[j].y);
                o.y = pack2(a[j].z, a[j].w);
                o.z = pack2(b[j].x, b[j].y);
                o.w = pack2(b[j].z, b[j].w);
                __builtin_nontemporal_store(o, out8 + g);
            }
        }
        for (; i < total8; i += nthr) {
            f32x4 a = __builtin_nontemporal_load(in4 + 2 * i);
            f32x4 b = __builtin_nontemporal_load(in4 + 2 * i + 1);
            u32x4 o;
            o.x = pack2(a.x, a.y);
            o.y = pack2(a.z, a.w);
            o.z = pack2(b.x, b.y);
            o.w = pack2(b.z, b.w);
            __builtin_nontemporal_store(o, out8 + i);
        }
        return;
    }

    // ---- weight combine: o = bid
    __shared__ float w2s[FDIM];
    __shared__ float rv[4], ru[4];
    int o = bid;

    for (size_t n = (size_t)o * 256 + tid; n < (size_t)N; n += 65536)
        deg[n] = feats[n * FDIM];

    w2s[tid] = W2[(size_t)o * K2 + FDIM + tid];
    __syncthreads();

    const float* w1a = W1 + tid;           // column k0 = tid       -> C1
    const float* w1b = W1 + FDIM + tid;    // column k1 = 256+tid   -> c2 sum
    float acc0 = 0.f, acc1 = 0.f;
    for (int j = 0; j < FDIM; j += 8) {
        float r0[8], r1[8];
        #pragma unroll
        for (int u = 0; u < 8; ++u) {
            r0[u] = w1a[(size_t)(j + u) * K2];
            r1[u] = w1b[(size_t)(j + u) * K2];
        }
        #pragma unroll
        for (int u = 0; u < 8; ++u) {
            acc0 = fmaf(w2s[j + u], r0[u], acc0);
            acc1 = fmaf(w2s[j + u], r1[u], acc1);
        }
    }
    g_Wc[(size_t)o * K2 + FDIM + tid] = f2bf(acc0);
    g_Wc[(size_t)o * K2 + tid]        = f2bf(W2[(size_t)o * K2 + tid]);

    float v = acc1;
    float u = b1[tid] * w2s[tid];
    #pragma unroll
    for (int s = 32; s; s >>= 1) { v += __shfl_down(v, s); u += __shfl_down(u, s); }
    if ((tid & 63) == 0) { rv[tid >> 6] = v; ru[tid >> 6] = u; }
    __syncthreads();
    if (tid == 0) {
        g_c2[o] = rv[0] + rv[1] + rv[2] + rv[3];
        g_c3[o] = b2[o] + Dmul * (ru[0] + ru[1] + ru[2] + ru[3]);
    }
}

// ---------- 2) gather (R8-validated, barrier-free): 1 wave/node, 8 rows in flight ----------
__global__ __launch_bounds__(256, 8) void gather(
    const unsigned short* tab_p, const float* deg_p,
    const int* __restrict__ adj,
    const int* __restrict__ in1, int B1,
    const int* __restrict__ in2, int B2,
    const int* __restrict__ neg, int total,
    unsigned short* X_p, float* Sdeg_p)
{
    const unsigned short* tab = tab_p ? tab_p : g_FDb;
    const float* deg = deg_p ? deg_p : g_degb;
    unsigned short* X = X_p ? X_p : g_Xb;
    float* Sdeg = Sdeg_p ? Sdeg_p : g_Sdegb;

    int wave = threadIdx.x >> 6, lane = threadIdx.x & 63;
    int t = blockIdx.x * 4 + wave;
    if (t >= total) return;
    int node = (t < B1) ? in1[t] : ((t < B1 + B2) ? in2[t - B1] : neg[t - B1 - B2]);

    int idx = 0; float dg = 0.f;
    if (lane < DNB) {
        idx = adj[(size_t)node * DNB + lane];
        dg = deg[idx];
    }
    #pragma unroll
    for (int s = 16; s; s >>= 1) dg += __shfl_down(dg, s);
    if (lane == 0) Sdeg[t] = dg;

    // node row passthrough (bf16): 8B/lane = full 512B row per wave-load
    ushort4 nf = *(const ushort4*)(tab + (size_t)node * FDIM + lane * 4);
    *(ushort4*)(X + (size_t)t * K2 + lane * 4) = nf;

    float a0 = 0.f, a1 = 0.f, a2 = 0.f, a3 = 0.f;
    #pragma unroll
    for (int d = 0; d < DNB; d += 8) {
        ushort4 v[8];
        #pragma unroll
        for (int u = 0; u < 8; ++u) {
            int nb = __shfl(idx, d + u);
            v[u] = *(const ushort4*)(tab + (size_t)nb * FDIM + lane * 4);
        }
        #pragma unroll
        for (int u = 0; u < 8; ++u) {
            a0 += bf2f(v[u].x);
            a1 += bf2f(v[u].y);
            a2 += bf2f(v[u].z);
            a3 += bf2f(v[u].w);
        }
    }
    *(ushort4*)(X + (size_t)t * K2 + FDIM + lane * 4) =
        make_ushort4(f2bf(a0), f2bf(a1), f2bf(a2), f2bf(a3));
}

// ---------- 3) gemm_norm (R8-validated): MFMA + degree term + L2 normalize ----------
__global__ __launch_bounds__(256, 4) void gemm_norm(const unsigned short* X_p,
                                                    const float* Sdeg_p,
                                                    float* __restrict__ out, int total)
{
    const unsigned short* X = X_p ? X_p : g_Xb;
    const float* SdegG = Sdeg_p ? Sdeg_p : g_Sdegb;

    __shared__ __align__(16) char lds[TM * 1024];  // bf16 [32][512]; reused f32 [32][256]
    __shared__ float Sdeg[TM];

    int tid = threadIdx.x, wave = tid >> 6, lane = tid & 63;
    int base = blockIdx.x * TM;

    if (tid < TM) {
        int t = base + tid;
        Sdeg[tid] = (t < total) ? SdegG[t] : 0.f;
    }
    #pragma unroll
    for (int i = 0; i < 8; ++i) {
        int row = wave * 8 + i;
        int t = base + row;
        bf16x8 v = {0, 0, 0, 0, 0, 0, 0, 0};
        if (t < total) v = *(const bf16x8*)(X + (size_t)t * K2 + lane * 8);
        *(bf16x8*)(lds + row * 1024 + ((lane * 16) ^ ((row & 7) << 4))) = v;
    }
    __syncthreads();

    int l15 = lane & 15, lg = lane >> 4;
    int swzA = (l15 & 7) << 4;
    f32x4 acc[2][4];
    #pragma unroll
    for (int mt = 0; mt < 2; ++mt)
        #pragma unroll
        for (int nt = 0; nt < 4; ++nt) acc[mt][nt] = (f32x4){0.f, 0.f, 0.f, 0.f};

    const char* pA0 = lds + (size_t)l15 * 1024;
    const char* pA1 = lds + (size_t)(16 + l15) * 1024;
    const unsigned short* wcB = g_Wc + (size_t)(wave * 64 + l15) * K2 + lg * 8;

    #pragma unroll 4
    for (int kk = 0; kk < K2; kk += 32) {
        int kb = kk * 2 + lg * 16;
        bf16x8 a0 = *(const bf16x8*)(pA0 + (kb ^ swzA));
        bf16x8 a1 = *(const bf16x8*)(pA1 + (kb ^ swzA));
        #pragma unroll
        for (int nt = 0; nt < 4; ++nt) {
            bf16x8 b = *(const bf16x8*)(wcB + (size_t)nt * 16 * K2 + kk);
            acc[0][nt] = __builtin_amdgcn_mfma_f32_16x16x32_bf16(a0, b, acc[0][nt], 0, 0, 0);
            acc[1][nt] = __builtin_amdgcn_mfma_f32_16x16x32_bf16(a1, b, acc[1][nt], 0, 0, 0);
        }
    }
    __syncthreads();

    float* outf = (float*)lds;
    #pragma unroll
    for (int mt = 0; mt < 2; ++mt)
        #pragma unroll
        for (int nt = 0; nt < 4; ++nt)
            #pragma unroll
            for (int r = 0; r < 4; ++r) {
                int row = mt * 16 + lg * 4 + r;
                int col = wave * 64 + nt * 16 + l15;
                outf[row * 256 + col] = acc[mt][nt][r];
            }
    __syncthreads();

    float4 c2v = *(const float4*)(g_c2 + lane * 4);
    float4 c3v = *(const float4*)(g_c3 + lane * 4);
    for (int r = 0; r < 8; ++r) {
        int row = wave * 8 + r;
        int t = base + row;
        if (t >= total) break;                   // wave-uniform
        float sd = Sdeg[row];
        float4 v = *(float4*)(outf + row * 256 + lane * 4);
        v.x += sd * c2v.x + c3v.x;
        v.y += sd * c2v.y + c3v.y;
        v.z += sd * c2v.z + c3v.z;
        v.w += sd * c2v.w + c3v.w;
        float ss = v.x * v.x + v.y * v.y + v.z * v.z + v.w * v.w;
        #pragma unroll
        for (int s = 32; s; s >>= 1) ss += __shfl_xor(ss, s);
        float inv = 1.0f / fmaxf(sqrtf(ss), 1e-12f);
        v.x *= inv; v.y *= inv; v.z *= inv; v.w *= inv;
        *(float4*)(out + (size_t)t * FDIM + lane * 4) = v;
    }
}

extern "C" void kernel_launch(void* const* d_in, const int* in_sizes, int n_in,
                              void* d_out, int out_size, void* d_ws, size_t ws_size,
                              hipStream_t stream) {
    const float* feat_data = (const float*)d_in[0];
    const float* feats     = (const float*)d_in[1];
    const float* W1        = (const float*)d_in[2];
    const float* b1        = (const float*)d_in[3];
    const float* W2        = (const float*)d_in[4];
    const float* b2        = (const float*)d_in[5];
    const int*   adj       = (const int*)d_in[6];
    const int*   in1       = (const int*)d_in[7];
    const int*   in2       = (const int*)d_in[8];
    const int*   neg       = (const int*)d_in[9];

    int B1 = in_sizes[7];
    int B2 = in_sizes[8];
    int Bn = in_sizes[9];
    int N  = in_sizes[0] / FDIM;
    int D  = in_sizes[6] / N;   // == 32

    float* out = (float*)d_out;
    int total = B1 + B2 + Bn;

    // ws layout: [tab bf16 N*256][X bf16 total*512][deg f32 N][Sdeg f32 total]
    size_t off = 0;
    auto take = [&](size_t bytes) { size_t o = off; off = (off + bytes + 255) & ~(size_t)255; return o; };
    size_t tab_o  = take((size_t)N * FDIM * 2);
    size_t x_o    = take((size_t)total * K2 * 2);
    size_t deg_o  = take((size_t)N * 4);
    size_t sdeg_o = take((size_t)total * 4);
    bool usews = (ws_size >= off);

    char* wsb = (char*)d_ws;
    unsigned short* tab = usews ? (unsigned short*)(wsb + tab_o) : nullptr;
    unsigned short* X   = usews ? (unsigned short*)(wsb + x_o)   : nullptr;
    float* deg  = usews ? (float*)(wsb + deg_o)  : nullptr;
    float* Sdeg = usews ? (float*)(wsb + sdeg_o) : nullptr;

    build_prep<<<256 + CONVB, 256, 0, stream>>>(feat_data, feats, W1, W2, b1, b2,
                                                (float)D, N, tab, deg);
    gather<<<(total + 3) / 4, 256, 0, stream>>>(tab, deg, adj, in1, B1, in2, B2,
                                                neg, total, X, Sdeg);
    gemm_norm<<<(total + TM - 1) / TM, 256, 0, stream>>>(X, Sdeg, out, total);
}

// Round 15
// 111.863 us; speedup vs baseline: 1.4891x; 1.0110x over previous
//
#include <hip/hip_runtime.h>
#include <hip/hip_bf16.h>

#define FDIM 256
#define K2   512
#define DNB  32
#define TM   32
#define NMAX 100000
#define TMAX 20480
#define CONVB 2048

typedef __attribute__((ext_vector_type(8))) short bf16x8;
typedef __attribute__((ext_vector_type(4))) float f32x4;
typedef __attribute__((ext_vector_type(4))) unsigned int u32x4;

// Fallback scratch in BSS (used only if ws_size is too small).
__device__ __align__(16) unsigned short g_FDb[(size_t)NMAX * FDIM];
__device__ __align__(16) unsigned short g_Xb[(size_t)TMAX * K2];
__device__ float g_degb[NMAX];
__device__ float g_Sdegb[TMAX];
// Small combined-weight arrays (L2-resident, read-heavy).
__device__ __align__(16) unsigned short g_Wc[FDIM * K2];   // [o][k] bf16
__device__ float g_c2[FDIM];
__device__ float g_c3[FDIM];

__device__ __forceinline__ unsigned short f2bf(float f) {
    __hip_bfloat16 h = __float2bfloat16(f);
    return *reinterpret_cast<unsigned short*>(&h);
}
__device__ __forceinline__ float bf2f(unsigned short u) {
    return __uint_as_float(((unsigned)u) << 16);
}
__device__ __forceinline__ unsigned int pack2(float lo, float hi) {
    return (unsigned int)f2bf(lo) | ((unsigned int)f2bf(hi) << 16);
}

// ---------- 1) build_prep: NT LOADS (read-once input) + REGULAR stores (L3-resident table)
__global__ __launch_bounds__(256) void build_prep(
    const float* __restrict__ fd,
    const float* __restrict__ feats,
    const float* __restrict__ W1,
    const float* __restrict__ W2,
    const float* __restrict__ b1,
    const float* __restrict__ b2,
    float Dmul, int N,
    unsigned short* tab_p, float* deg_p)
{
    unsigned short* tab = tab_p ? tab_p : g_FDb;
    float* deg = deg_p ? deg_p : g_degb;
    int bid = blockIdx.x;
    int tid = threadIdx.x;

    if (bid >= 256) {
        // ---- conversion: grid-stride, 4-deep, NT loads + REGULAR stores
        size_t tidg = (size_t)(bid - 256) * 256 + tid;
        size_t nthr = (size_t)CONVB * 256;
        size_t total8 = (size_t)N * (FDIM / 8);   // # 16B output groups
        const f32x4* in4 = (const f32x4*)fd;
        u32x4* out8 = (u32x4*)tab;

        size_t i = tidg;
        for (; i + 3 * nthr < total8; i += 4 * nthr) {
            f32x4 a[4], b[4];
            #pragma unroll
            for (int j = 0; j < 4; ++j) {
                size_t g = i + (size_t)j * nthr;
                a[j] = __builtin_nontemporal_load(in4 + 2 * g);
                b[j] = __builtin_nontemporal_load(in4 + 2 * g + 1);
            }
            #pragma unroll
            for (int j = 0; j < 4; ++j) {
                size_t g = i + (size_t)j * nthr;
                u32x4 o;
                o.x = pack2(a[j].x, a[j].y);
                o.y = pack2(a[j].z, a[j].w);
                o.z = pack2(b[j].x, b[j].y);
                o.w = pack2(b[j].z, b[j].w);
                out8[g] = o;
            }
        }
        for (; i < total8; i += nthr) {
            f32x4 a = __builtin_nontemporal_load(in4 + 2 * i);
            f32x4 b = __builtin_nontemporal_load(in4 + 2 * i + 1);
            u32x4 o;
            o.x = pack2(a.x, a.y);
            o.y = pack2(a.z, a.w);
            o.z = pack2(b.x, b.y);
            o.w = pack2(b.z, b.w);
            out8[i] = o;
        }
        return;
    }

    // ---- weight combine: o = bid
    __shared__ float w2s[FDIM];
    __shared__ float rv[4], ru[4];
    int o = bid;

    for (size_t n = (size_t)o * 256 + tid; n < (size_t)N; n += 65536)
        deg[n] = feats[n * FDIM];

    w2s[tid] = W2[(size_t)o * K2 + FDIM + tid];
    __syncthreads();

    const float* w1a = W1 + tid;           // column k0 = tid       -> C1
    const float* w1b = W1 + FDIM + tid;    // column k1 = 256+tid   -> c2 sum
    float acc0 = 0.f, acc1 = 0.f;
    for (int j = 0; j < FDIM; j += 8) {
        float r0[8], r1[8];
        #pragma unroll
        for (int u = 0; u < 8; ++u) {
            r0[u] = w1a[(size_t)(j + u) * K2];
            r1[u] = w1b[(size_t)(j + u) * K2];
        }
        #pragma unroll
        for (int u = 0; u < 8; ++u) {
            acc0 = fmaf(w2s[j + u], r0[u], acc0);
            acc1 = fmaf(w2s[j + u], r1[u], acc1);
        }
    }
    g_Wc[(size_t)o * K2 + FDIM + tid] = f2bf(acc0);
    g_Wc[(size_t)o * K2 + tid]        = f2bf(W2[(size_t)o * K2 + tid]);

    float v = acc1;
    float u = b1[tid] * w2s[tid];
    #pragma unroll
    for (int s = 32; s; s >>= 1) { v += __shfl_down(v, s); u += __shfl_down(u, s); }
    if ((tid & 63) == 0) { rv[tid >> 6] = v; ru[tid >> 6] = u; }
    __syncthreads();
    if (tid == 0) {
        g_c2[o] = rv[0] + rv[1] + rv[2] + rv[3];
        g_c3[o] = b2[o] + Dmul * (ru[0] + ru[1] + ru[2] + ru[3]);
    }
}

// ---------- 2) gather (R8-validated, barrier-free): 1 wave/node, 8 rows in flight ----------
__global__ __launch_bounds__(256, 8) void gather(
    const unsigned short* tab_p, const float* deg_p,
    const int* __restrict__ adj,
    const int* __restrict__ in1, int B1,
    const int* __restrict__ in2, int B2,
    const int* __restrict__ neg, int total,
    unsigned short* X_p, float* Sdeg_p)
{
    const unsigned short* tab = tab_p ? tab_p : g_FDb;
    const float* deg = deg_p ? deg_p : g_degb;
    unsigned short* X = X_p ? X_p : g_Xb;
    float* Sdeg = Sdeg_p ? Sdeg_p : g_Sdegb;

    int wave = threadIdx.x >> 6, lane = threadIdx.x & 63;
    int t = blockIdx.x * 4 + wave;
    if (t >= total) return;
    int node = (t < B1) ? in1[t] : ((t < B1 + B2) ? in2[t - B1] : neg[t - B1 - B2]);

    int idx = 0; float dg = 0.f;
    if (lane < DNB) {
        idx = adj[(size_t)node * DNB + lane];
        dg = deg[idx];
    }
    #pragma unroll
    for (int s = 16; s; s >>= 1) dg += __shfl_down(dg, s);
    if (lane == 0) Sdeg[t] = dg;

    // node row passthrough (bf16): 8B/lane = full 512B row per wave-load
    ushort4 nf = *(const ushort4*)(tab + (size_t)node * FDIM + lane * 4);
    *(ushort4*)(X + (size_t)t * K2 + lane * 4) = nf;

    float a0 = 0.f, a1 = 0.f, a2 = 0.f, a3 = 0.f;
    #pragma unroll
    for (int d = 0; d < DNB; d += 8) {
        ushort4 v[8];
        #pragma unroll
        for (int u = 0; u < 8; ++u) {
            int nb = __shfl(idx, d + u);
            v[u] = *(const ushort4*)(tab + (size_t)nb * FDIM + lane * 4);
        }
        #pragma unroll
        for (int u = 0; u < 8; ++u) {
            a0 += bf2f(v[u].x);
            a1 += bf2f(v[u].y);
            a2 += bf2f(v[u].z);
            a3 += bf2f(v[u].w);
        }
    }
    *(ushort4*)(X + (size_t)t * K2 + FDIM + lane * 4) =
        make_ushort4(f2bf(a0), f2bf(a1), f2bf(a2), f2bf(a3));
}

// ---------- 3) gemm_norm (R8-validated): MFMA + degree term + L2 normalize ----------
__global__ __launch_bounds__(256, 4) void gemm_norm(const unsigned short* X_p,
                                                    const float* Sdeg_p,
                                                    float* __restrict__ out, int total)
{
    const unsigned short* X = X_p ? X_p : g_Xb;
    const float* SdegG = Sdeg_p ? Sdeg_p : g_Sdegb;

    __shared__ __align__(16) char lds[TM * 1024];  // bf16 [32][512]; reused f32 [32][256]
    __shared__ float Sdeg[TM];

    int tid = threadIdx.x, wave = tid >> 6, lane = tid & 63;
    int base = blockIdx.x * TM;

    if (tid < TM) {
        int t = base + tid;
        Sdeg[tid] = (t < total) ? SdegG[t] : 0.f;
    }
    #pragma unroll
    for (int i = 0; i < 8; ++i) {
        int row = wave * 8 + i;
        int t = base + row;
        bf16x8 v = {0, 0, 0, 0, 0, 0, 0, 0};
        if (t < total) v = *(const bf16x8*)(X + (size_t)t * K2 + lane * 8);
        *(bf16x8*)(lds + row * 1024 + ((lane * 16) ^ ((row & 7) << 4))) = v;
    }
    __syncthreads();

    int l15 = lane & 15, lg = lane >> 4;
    int swzA = (l15 & 7) << 4;
    f32x4 acc[2][4];
    #pragma unroll
    for (int mt = 0; mt < 2; ++mt)
        #pragma unroll
        for (int nt = 0; nt < 4; ++nt) acc[mt][nt] = (f32x4){0.f, 0.f, 0.f, 0.f};

    const char* pA0 = lds + (size_t)l15 * 1024;
    const char* pA1 = lds + (size_t)(16 + l15) * 1024;
    const unsigned short* wcB = g_Wc + (size_t)(wave * 64 + l15) * K2 + lg * 8;

    #pragma unroll 4
    for (int kk = 0; kk < K2; kk += 32) {
        int kb = kk * 2 + lg * 16;
        bf16x8 a0 = *(const bf16x8*)(pA0 + (kb ^ swzA));
        bf16x8 a1 = *(const bf16x8*)(pA1 + (kb ^ swzA));
        #pragma unroll
        for (int nt = 0; nt < 4; ++nt) {
            bf16x8 b = *(const bf16x8*)(wcB + (size_t)nt * 16 * K2 + kk);
            acc[0][nt] = __builtin_amdgcn_mfma_f32_16x16x32_bf16(a0, b, acc[0][nt], 0, 0, 0);
            acc[1][nt] = __builtin_amdgcn_mfma_f32_16x16x32_bf16(a1, b, acc[1][nt], 0, 0, 0);
        }
    }
    __syncthreads();

    float* outf = (float*)lds;
    #pragma unroll
    for (int mt = 0; mt < 2; ++mt)
        #pragma unroll
        for (int nt = 0; nt < 4; ++nt)
            #pragma unroll
            for (int r = 0; r < 4; ++r) {
                int row = mt * 16 + lg * 4 + r;
                int col = wave * 64 + nt * 16 + l15;
                outf[row * 256 + col] = acc[mt][nt][r];
            }
    __syncthreads();

    float4 c2v = *(const float4*)(g_c2 + lane * 4);
    float4 c3v = *(const float4*)(g_c3 + lane * 4);
    for (int r = 0; r < 8; ++r) {
        int row = wave * 8 + r;
        int t = base + row;
        if (t >= total) break;                   // wave-uniform
        float sd = Sdeg[row];
        float4 v = *(float4*)(outf + row * 256 + lane * 4);
        v.x += sd * c2v.x + c3v.x;
        v.y += sd * c2v.y + c3v.y;
        v.z += sd * c2v.z + c3v.z;
        v.w += sd * c2v.w + c3v.w;
        float ss = v.x * v.x + v.y * v.y + v.z * v.z + v.w * v.w;
        #pragma unroll
        for (int s = 32; s; s >>= 1) ss += __shfl_xor(ss, s);
        float inv = 1.0f / fmaxf(sqrtf(ss), 1e-12f);
        f32x4 o;
        o.x = v.x * inv; o.y = v.y * inv; o.z = v.z * inv; o.w = v.w * inv;
        __builtin_nontemporal_store(o, (f32x4*)(out + (size_t)t * FDIM + lane * 4));
    }
}

extern "C" void kernel_launch(void* const* d_in, const int* in_sizes, int n_in,
                              void* d_out, int out_size, void* d_ws, size_t ws_size,
                              hipStream_t stream) {
    const float* feat_data = (const float*)d_in[0];
    const float* feats     = (const float*)d_in[1];
    const float* W1        = (const float*)d_in[2];
    const float* b1        = (const float*)d_in[3];
    const float* W2        = (const float*)d_in[4];
    const float* b2        = (const float*)d_in[5];
    const int*   adj       = (const int*)d_in[6];
    const int*   in1       = (const int*)d_in[7];
    const int*   in2       = (const int*)d_in[8];
    const int*   neg       = (const int*)d_in[9];

    int B1 = in_sizes[7];
    int B2 = in_sizes[8];
    int Bn = in_sizes[9];
    int N  = in_sizes[0] / FDIM;
    int D  = in_sizes[6] / N;   // == 32

    float* out = (float*)d_out;
    int total = B1 + B2 + Bn;

    // ws layout: [tab bf16 N*256][X bf16 total*512][deg f32 N][Sdeg f32 total]
    size_t off = 0;
    auto take = [&](size_t bytes) { size_t o = off; off = (off + bytes + 255) & ~(size_t)255; return o; };
    size_t tab_o  = take((size_t)N * FDIM * 2);
    size_t x_o    = take((size_t)total * K2 * 2);
    size_t deg_o  = take((size_t)N * 4);
    size_t sdeg_o = take((size_t)total * 4);
    bool usews = (ws_size >= off);

    char* wsb = (char*)d_ws;
    unsigned short* tab = usews ? (unsigned short*)(wsb + tab_o) : nullptr;
    unsigned short* X   = usews ? (unsigned short*)(wsb + x_o)   : nullptr;
    float* deg  = usews ? (float*)(wsb + deg_o)  : nullptr;
    float* Sdeg = usews ? (float*)(wsb + sdeg_o) : nullptr;

    build_prep<<<256 + CONVB, 256, 0, stream>>>(feat_data, feats, W1, W2, b1, b2,
                                                (float)D, N, tab, deg);
    gather<<<(total + 3) / 4, 256, 0, stream>>>(tab, deg, adj, in1, B1, in2, B2,
                                                neg, total, X, Sdeg);
    gemm_norm<<<(total + TM - 1) / TM, 256, 0, stream>>>(X, Sdeg, out, total);
}

// Round 16
// 100.630 us; speedup vs baseline: 1.6554x; 1.1116x over previous
//
#include <hip/hip_runtime.h>
#include <hip/hip_bf16.h>
#include <hip/hip_fp8.h>

#define FDIM 256
#define K2   512
#define DNB  32
#define TM   32
#define NMAX 100000
#define TMAX 20480
#define CONVB 2048

typedef __attribute__((ext_vector_type(8))) short bf16x8;
typedef __attribute__((ext_vector_type(4))) float f32x4;
typedef __attribute__((ext_vector_type(2))) float f32x2;
typedef __attribute__((ext_vector_type(4))) unsigned int u32x4;
typedef __attribute__((ext_vector_type(2))) unsigned int u32x2;

// Fallback scratch in BSS (used only if ws_size is too small).
__device__ __align__(16) unsigned char g_FDb[(size_t)NMAX * FDIM];   // fp8 table
__device__ __align__(16) unsigned short g_Xb[(size_t)TMAX * K2];
__device__ float g_degb[NMAX];
__device__ float g_Sdegb[TMAX];
// Small combined-weight arrays (L2-resident, read-heavy).
__device__ __align__(16) unsigned short g_Wc[FDIM * K2];   // [o][k] bf16
__device__ float g_c2[FDIM];
__device__ float g_c3[FDIM];

__device__ __forceinline__ unsigned short f2bf(float f) {
    __hip_bfloat16 h = __float2bfloat16(f);
    return *reinterpret_cast<unsigned short*>(&h);
}

// fp8 e4m3 pack/unpack (HW cvt when available; round-trip is self-consistent)
__device__ __forceinline__ unsigned int enc4(float a, float b, float c, float d) {
#if __has_builtin(__builtin_amdgcn_cvt_pk_fp8_f32)
    int w = 0;
    w = __builtin_amdgcn_cvt_pk_fp8_f32(a, b, w, false);
    w = __builtin_amdgcn_cvt_pk_fp8_f32(c, d, w, true);
    return (unsigned int)w;
#else
    __hip_fp8_e4m3 ha(a), hb(b), hc(c), hd(d);
    return (unsigned)ha.__x | ((unsigned)hb.__x << 8) |
           ((unsigned)hc.__x << 16) | ((unsigned)hd.__x << 24);
#endif
}
__device__ __forceinline__ f32x4 dec4(unsigned int w) {
#if __has_builtin(__builtin_amdgcn_cvt_pk_f32_fp8)
    f32x2 lo = __builtin_amdgcn_cvt_pk_f32_fp8((int)w, false);
    f32x2 hi = __builtin_amdgcn_cvt_pk_f32_fp8((int)w, true);
    return (f32x4){lo.x, lo.y, hi.x, hi.y};
#else
    __hip_fp8_e4m3 h0, h1, h2, h3;
    h0.__x = (unsigned char)(w);
    h1.__x = (unsigned char)(w >> 8);
    h2.__x = (unsigned char)(w >> 16);
    h3.__x = (unsigned char)(w >> 24);
    return (f32x4){(float)h0, (float)h1, (float)h2, (float)h3};
#endif
}

// ---------- 1) build_prep: NT loads + REGULAR stores; fp8 table (25.6 MB) ----------
__global__ __launch_bounds__(256) void build_prep(
    const float* __restrict__ fd,
    const float* __restrict__ feats,
    const float* __restrict__ W1,
    const float* __restrict__ W2,
    const float* __restrict__ b1,
    const float* __restrict__ b2,
    float Dmul, int N,
    unsigned char* tab_p, float* deg_p)
{
    unsigned char* tab = tab_p ? tab_p : g_FDb;
    float* deg = deg_p ? deg_p : g_degb;
    int bid = blockIdx.x;
    int tid = threadIdx.x;

    if (bid >= 256) {
        // conversion: each group = 64B fp32 in -> 16B fp8 out; 2-deep grid-stride
        size_t tidg = (size_t)(bid - 256) * 256 + tid;
        size_t nthr = (size_t)CONVB * 256;
        size_t total16 = (size_t)N * (FDIM / 16);
        const f32x4* in4 = (const f32x4*)fd;
        u32x4* out16 = (u32x4*)tab;

        size_t i = tidg;
        for (; i + nthr < total16; i += 2 * nthr) {
            f32x4 a0 = __builtin_nontemporal_load(in4 + 4 * i);
            f32x4 a1 = __builtin_nontemporal_load(in4 + 4 * i + 1);
            f32x4 a2 = __builtin_nontemporal_load(in4 + 4 * i + 2);
            f32x4 a3 = __builtin_nontemporal_load(in4 + 4 * i + 3);
            size_t j = i + nthr;
            f32x4 b0 = __builtin_nontemporal_load(in4 + 4 * j);
            f32x4 b1v = __builtin_nontemporal_load(in4 + 4 * j + 1);
            f32x4 b2v = __builtin_nontemporal_load(in4 + 4 * j + 2);
            f32x4 b3 = __builtin_nontemporal_load(in4 + 4 * j + 3);
            u32x4 oa, ob;
            oa.x = enc4(a0.x, a0.y, a0.z, a0.w);
            oa.y = enc4(a1.x, a1.y, a1.z, a1.w);
            oa.z = enc4(a2.x, a2.y, a2.z, a2.w);
            oa.w = enc4(a3.x, a3.y, a3.z, a3.w);
            ob.x = enc4(b0.x, b0.y, b0.z, b0.w);
            ob.y = enc4(b1v.x, b1v.y, b1v.z, b1v.w);
            ob.z = enc4(b2v.x, b2v.y, b2v.z, b2v.w);
            ob.w = enc4(b3.x, b3.y, b3.z, b3.w);
            out16[i] = oa;
            out16[j] = ob;
        }
        for (; i < total16; i += nthr) {
            f32x4 a0 = __builtin_nontemporal_load(in4 + 4 * i);
            f32x4 a1 = __builtin_nontemporal_load(in4 + 4 * i + 1);
            f32x4 a2 = __builtin_nontemporal_load(in4 + 4 * i + 2);
            f32x4 a3 = __builtin_nontemporal_load(in4 + 4 * i + 3);
            u32x4 o;
            o.x = enc4(a0.x, a0.y, a0.z, a0.w);
            o.y = enc4(a1.x, a1.y, a1.z, a1.w);
            o.z = enc4(a2.x, a2.y, a2.z, a2.w);
            o.w = enc4(a3.x, a3.y, a3.z, a3.w);
            out16[i] = o;
        }
        return;
    }

    // ---- weight combine: o = bid
    __shared__ float w2s[FDIM];
    __shared__ float rv[4], ru[4];
    int o = bid;

    for (size_t n = (size_t)o * 256 + tid; n < (size_t)N; n += 65536)
        deg[n] = feats[n * FDIM];

    w2s[tid] = W2[(size_t)o * K2 + FDIM + tid];
    __syncthreads();

    const float* w1a = W1 + tid;           // column k0 = tid       -> C1
    const float* w1b = W1 + FDIM + tid;    // column k1 = 256+tid   -> c2 sum
    float acc0 = 0.f, acc1 = 0.f;
    for (int j = 0; j < FDIM; j += 8) {
        float r0[8], r1[8];
        #pragma unroll
        for (int u = 0; u < 8; ++u) {
            r0[u] = w1a[(size_t)(j + u) * K2];
            r1[u] = w1b[(size_t)(j + u) * K2];
        }
        #pragma unroll
        for (int u = 0; u < 8; ++u) {
            acc0 = fmaf(w2s[j + u], r0[u], acc0);
            acc1 = fmaf(w2s[j + u], r1[u], acc1);
        }
    }
    g_Wc[(size_t)o * K2 + FDIM + tid] = f2bf(acc0);
    g_Wc[(size_t)o * K2 + tid]        = f2bf(W2[(size_t)o * K2 + tid]);

    float v = acc1;
    float u = b1[tid] * w2s[tid];
    #pragma unroll
    for (int s = 32; s; s >>= 1) { v += __shfl_down(v, s); u += __shfl_down(u, s); }
    if ((tid & 63) == 0) { rv[tid >> 6] = v; ru[tid >> 6] = u; }
    __syncthreads();
    if (tid == 0) {
        g_c2[o] = rv[0] + rv[1] + rv[2] + rv[3];
        g_c3[o] = b2[o] + Dmul * (ru[0] + ru[1] + ru[2] + ru[3]);
    }
}

// ---------- 2) gather: fp8 rows, half-wave (8B/lane), 1 wave/node ----------
__global__ __launch_bounds__(256, 8) void gather(
    const unsigned char* tab_p, const float* deg_p,
    const int* __restrict__ adj,
    const int* __restrict__ in1, int B1,
    const int* __restrict__ in2, int B2,
    const int* __restrict__ neg, int total,
    unsigned short* X_p, float* Sdeg_p)
{
    const unsigned char* tab = tab_p ? tab_p : g_FDb;
    const float* deg = deg_p ? deg_p : g_degb;
    unsigned short* X = X_p ? X_p : g_Xb;
    float* Sdeg = Sdeg_p ? Sdeg_p : g_Sdegb;

    int wave = threadIdx.x >> 6, lane = threadIdx.x & 63;
    int half = lane >> 5, l31 = lane & 31;
    int t = blockIdx.x * 4 + wave;
    if (t >= total) return;
    int node = (t < B1) ? in1[t] : ((t < B1 + B2) ? in2[t - B1] : neg[t - B1 - B2]);

    int idx = 0; float dg = 0.f;
    if (lane < DNB) {
        idx = adj[(size_t)node * DNB + lane];
        dg = deg[idx];
    }
    #pragma unroll
    for (int s = 16; s; s >>= 1) dg += __shfl_down(dg, s);
    if (lane == 0) Sdeg[t] = dg;

    // NF passthrough: 4 fp8 per lane -> 4 bf16 (full 256B row per wave)
    unsigned int nw = *(const unsigned int*)(tab + (size_t)node * FDIM + lane * 4);
    f32x4 nf = dec4(nw);
    *(ushort4*)(X + (size_t)t * K2 + lane * 4) =
        make_ushort4(f2bf(nf.x), f2bf(nf.y), f2bf(nf.z), f2bf(nf.w));

    // neighbor sum: half-wave h covers neighbors d+2u+h; lane covers cols l31*8..+7
    float acc[8];
    #pragma unroll
    for (int k = 0; k < 8; ++k) acc[k] = 0.f;
    #pragma unroll
    for (int d = 0; d < DNB; d += 16) {
        u32x2 v[8];
        #pragma unroll
        for (int u = 0; u < 8; ++u) {
            int nb = __shfl(idx, d + u * 2 + half);
            v[u] = *(const u32x2*)(tab + (size_t)nb * FDIM + l31 * 8);
        }
        #pragma unroll
        for (int u = 0; u < 8; ++u) {
            f32x4 lo = dec4(v[u].x);
            f32x4 hi = dec4(v[u].y);
            acc[0] += lo.x; acc[1] += lo.y; acc[2] += lo.z; acc[3] += lo.w;
            acc[4] += hi.x; acc[5] += hi.y; acc[6] += hi.z; acc[7] += hi.w;
        }
    }
    // combine even/odd-neighbor halves
    #pragma unroll
    for (int k = 0; k < 8; ++k) acc[k] += __shfl_xor(acc[k], 32);

    if (lane < 32) {
        bf16x8 ah;
        #pragma unroll
        for (int k = 0; k < 8; ++k) ah[k] = (short)f2bf(acc[k]);
        *(bf16x8*)(X + (size_t)t * K2 + FDIM + l31 * 8) = ah;
    }
}

// ---------- 3) gemm_norm (R8-validated): MFMA + degree term + L2 normalize ----------
__global__ __launch_bounds__(256, 4) void gemm_norm(const unsigned short* X_p,
                                                    const float* Sdeg_p,
                                                    float* __restrict__ out, int total)
{
    const unsigned short* X = X_p ? X_p : g_Xb;
    const float* SdegG = Sdeg_p ? Sdeg_p : g_Sdegb;

    __shared__ __align__(16) char lds[TM * 1024];  // bf16 [32][512]; reused f32 [32][256]
    __shared__ float Sdeg[TM];

    int tid = threadIdx.x, wave = tid >> 6, lane = tid & 63;
    int base = blockIdx.x * TM;

    if (tid < TM) {
        int t = base + tid;
        Sdeg[tid] = (t < total) ? SdegG[t] : 0.f;
    }
    #pragma unroll
    for (int i = 0; i < 8; ++i) {
        int row = wave * 8 + i;
        int t = base + row;
        bf16x8 v = {0, 0, 0, 0, 0, 0, 0, 0};
        if (t < total) v = *(const bf16x8*)(X + (size_t)t * K2 + lane * 8);
        *(bf16x8*)(lds + row * 1024 + ((lane * 16) ^ ((row & 7) << 4))) = v;
    }
    __syncthreads();

    int l15 = lane & 15, lg = lane >> 4;
    int swzA = (l15 & 7) << 4;
    f32x4 acc[2][4];
    #pragma unroll
    for (int mt = 0; mt < 2; ++mt)
        #pragma unroll
        for (int nt = 0; nt < 4; ++nt) acc[mt][nt] = (f32x4){0.f, 0.f, 0.f, 0.f};

    const char* pA0 = lds + (size_t)l15 * 1024;
    const char* pA1 = lds + (size_t)(16 + l15) * 1024;
    const unsigned short* wcB = g_Wc + (size_t)(wave * 64 + l15) * K2 + lg * 8;

    #pragma unroll 4
    for (int kk = 0; kk < K2; kk += 32) {
        int kb = kk * 2 + lg * 16;
        bf16x8 a0 = *(const bf16x8*)(pA0 + (kb ^ swzA));
        bf16x8 a1 = *(const bf16x8*)(pA1 + (kb ^ swzA));
        #pragma unroll
        for (int nt = 0; nt < 4; ++nt) {
            bf16x8 b = *(const bf16x8*)(wcB + (size_t)nt * 16 * K2 + kk);
            acc[0][nt] = __builtin_amdgcn_mfma_f32_16x16x32_bf16(a0, b, acc[0][nt], 0, 0, 0);
            acc[1][nt] = __builtin_amdgcn_mfma_f32_16x16x32_bf16(a1, b, acc[1][nt], 0, 0, 0);
        }
    }
    __syncthreads();

    float* outf = (float*)lds;
    #pragma unroll
    for (int mt = 0; mt < 2; ++mt)
        #pragma unroll
        for (int nt = 0; nt < 4; ++nt)
            #pragma unroll
            for (int r = 0; r < 4; ++r) {
                int row = mt * 16 + lg * 4 + r;
                int col = wave * 64 + nt * 16 + l15;
                outf[row * 256 + col] = acc[mt][nt][r];
            }
    __syncthreads();

    float4 c2v = *(const float4*)(g_c2 + lane * 4);
    float4 c3v = *(const float4*)(g_c3 + lane * 4);
    for (int r = 0; r < 8; ++r) {
        int row = wave * 8 + r;
        int t = base + row;
        if (t >= total) break;                   // wave-uniform
        float sd = Sdeg[row];
        float4 v = *(float4*)(outf + row * 256 + lane * 4);
        v.x += sd * c2v.x + c3v.x;
        v.y += sd * c2v.y + c3v.y;
        v.z += sd * c2v.z + c3v.z;
        v.w += sd * c2v.w + c3v.w;
        float ss = v.x * v.x + v.y * v.y + v.z * v.z + v.w * v.w;
        #pragma unroll
        for (int s = 32; s; s >>= 1) ss += __shfl_xor(ss, s);
        float inv = 1.0f / fmaxf(sqrtf(ss), 1e-12f);
        f32x4 o;
        o.x = v.x * inv; o.y = v.y * inv; o.z = v.z * inv; o.w = v.w * inv;
        __builtin_nontemporal_store(o, (f32x4*)(out + (size_t)t * FDIM + lane * 4));
    }
}

extern "C" void kernel_launch(void* const* d_in, const int* in_sizes, int n_in,
                              void* d_out, int out_size, void* d_ws, size_t ws_size,
                              hipStream_t stream) {
    const float* feat_data = (const float*)d_in[0];
    const float* feats     = (const float*)d_in[1];
    const float* W1        = (const float*)d_in[2];
    const float* b1        = (const float*)d_in[3];
    const float* W2        = (const float*)d_in[4];
    const float* b2        = (const float*)d_in[5];
    const int*   adj       = (const int*)d_in[6];
    const int*   in1       = (const int*)d_in[7];
    const int*   in2       = (const int*)d_in[8];
    const int*   neg       = (const int*)d_in[9];

    int B1 = in_sizes[7];
    int B2 = in_sizes[8];
    int Bn = in_sizes[9];
    int N  = in_sizes[0] / FDIM;
    int D  = in_sizes[6] / N;   // == 32

    float* out = (float*)d_out;
    int total = B1 + B2 + Bn;

    // ws layout: [tab fp8 N*256][X bf16 total*512][deg f32 N][Sdeg f32 total]
    size_t off = 0;
    auto take = [&](size_t bytes) { size_t o = off; off = (off + bytes + 255) & ~(size_t)255; return o; };
    size_t tab_o  = take((size_t)N * FDIM);
    size_t x_o    = take((size_t)total * K2 * 2);
    size_t deg_o  = take((size_t)N * 4);
    size_t sdeg_o = take((size_t)total * 4);
    bool usews = (ws_size >= off);

    char* wsb = (char*)d_ws;
    unsigned char* tab  = usews ? (unsigned char*)(wsb + tab_o) : nullptr;
    unsigned short* X   = usews ? (unsigned short*)(wsb + x_o)  : nullptr;
    float* deg  = usews ? (float*)(wsb + deg_o)  : nullptr;
    float* Sdeg = usews ? (float*)(wsb + sdeg_o) : nullptr;

    build_prep<<<256 + CONVB, 256, 0, stream>>>(feat_data, feats, W1, W2, b1, b2,
                                                (float)D, N, tab, deg);
    gather<<<(total + 3) / 4, 256, 0, stream>>>(tab, deg, adj, in1, B1, in2, B2,
                                                neg, total, X, Sdeg);
    gemm_norm<<<(total + TM - 1) / TM, 256, 0, stream>>>(X, Sdeg, out, total);
}